// Round 10
// baseline (217.768 us; speedup 1.0000x reference)
//
#include <hip/hip_runtime.h>

#define N 9216
#define CIN 256
#define DQ 32
#define NT 144                      // N / 64
#define LOG2E 1.44269504088896340736f

typedef short short8 __attribute__((ext_vector_type(8)));   // 8 bf16 in 4 VGPRs
typedef float floatx4 __attribute__((ext_vector_type(4)));
typedef unsigned short ushort_t;

__device__ __forceinline__ ushort_t f2bf(float f) {
  union { float f; unsigned u; } a; a.f = f;
  unsigned u = a.u;
  u += 0x7fffu + ((u >> 16) & 1u);   // round-to-nearest-even
  return (ushort_t)(u >> 16);
}
// cheap round-to-nearest: 2 VALU ops instead of 5.
__device__ __forceinline__ ushort_t f2bf_fast(float f) {
  union { float f; unsigned u; } a; a.f = f;
  return (ushort_t)((a.u + 0x8000u) >> 16);
}
__device__ __forceinline__ float bf2f(ushort_t h) {
  union { unsigned u; float f; } a; a.u = ((unsigned)h) << 16;
  return a.f;
}
// pack two floats -> one uint of 2 bf16 (lo = c, hi = c1)
__device__ __forceinline__ unsigned pack2(float lo, float hi) {
  return ((unsigned)f2bf_fast(hi) << 16) | (unsigned)f2bf_fast(lo);
}
// 8 consecutive fp32 -> bf16x8 A-fragment
__device__ __forceinline__ short8 mk_bf16x8(const float* p) {
  float4 f0 = *(const float4*)(p);
  float4 f1 = *(const float4*)(p + 4);
  union { unsigned u[4]; short8 v; } r;
  r.u[0] = pack2(f0.x, f0.y);
  r.u[1] = pack2(f0.z, f0.w);
  r.u[2] = pack2(f1.x, f1.y);
  r.u[3] = pack2(f1.z, f1.w);
  return r.v;
}

// LDS-visibility-only barrier: drains lgkmcnt (LDS) but leaves global
// register loads (vmcnt) in flight across the rendezvous.
__device__ __forceinline__ void barrier_lds_only() {
  asm volatile("s_waitcnt lgkmcnt(0)" ::: "memory");
  __builtin_amdgcn_s_barrier();
  asm volatile("" ::: "memory");
}

// ---------------------------------------------------------------------------
// Shared staging: x tile (256 c x 64 n) -> LDS bf16 xbT[n][k=c].
// ---------------------------------------------------------------------------
#define XBT_STRIDE 264   // ushorts per row (256 + 8 pad); 132 uints

__device__ __forceinline__ void stage_x_tile(
    const float* __restrict__ x, int n0, int t, ushort_t (*xbT)[XBT_STRIDE])
{
  const int p = t & 31, ng = t >> 5;          // ng in [0,8)
  unsigned* base = (unsigned*)&xbT[0][0] + (size_t)(ng * 8) * 132;
#pragma unroll
  for (int cc = 0; cc < 4; ++cc) {
    const int c = cc * 64 + 2 * p;
    const float* r0 = x + (size_t)c * N + n0 + ng * 8;
    const float* r1 = r0 + N;
    float4 a0 = *(const float4*)(r0);
    float4 a1 = *(const float4*)(r0 + 4);
    float4 b0 = *(const float4*)(r1);
    float4 b1 = *(const float4*)(r1 + 4);
    unsigned* d = base + (cc * 32 + p);
    d[0 * 132] = pack2(a0.x, b0.x);
    d[1 * 132] = pack2(a0.y, b0.y);
    d[2 * 132] = pack2(a0.z, b0.z);
    d[3 * 132] = pack2(a0.w, b0.w);
    d[4 * 132] = pack2(a1.x, b1.x);
    d[5 * 132] = pack2(a1.y, b1.y);
    d[6 * 132] = pack2(a1.z, b1.z);
    d[7 * 132] = pack2(a1.w, b1.w);
  }
}

// ---------------------------------------------------------------------------
// Kernel 1: q/k/v projections via bf16 MFMA.  UNCHANGED (control, R5 form).
// ---------------------------------------------------------------------------
__global__ __launch_bounds__(256) void qkv_mfma(
    const float* __restrict__ x,
    const float* __restrict__ Wq, const float* __restrict__ bq,
    const float* __restrict__ Wk, const float* __restrict__ bk,
    const float* __restrict__ Wv, const float* __restrict__ bv,
    ushort_t* __restrict__ qT, ushort_t* __restrict__ kT,
    ushort_t* __restrict__ vG, float* __restrict__ sumExp)
{
  if (blockIdx.x == 0 && blockIdx.y == 0 && threadIdx.x == 0) *sumExp = 0.f;

  __shared__ ushort_t xbT[64][XBT_STRIDE];
  const int t = threadIdx.x;
  const int n0 = blockIdx.x * 64;
  const int oc = blockIdx.y;                 // 0: q(32)+k(32); 1..4: v
  const int w = t >> 6, lane = t & 63;
  const int quad = lane >> 4, l15 = lane & 15;

  stage_x_tile(x, n0, t, xbT);
  __syncthreads();

  const int obase = oc * 64 + w * 16;
  const int oA = obase + l15;                // A-frag row (m = l15)
  const float* Arow;
  if (oc == 0) Arow = (obase < 32) ? (Wq + (size_t)oA * CIN)
                                   : (Wk + (size_t)(oA - 32) * CIN);
  else         Arow = Wv + (size_t)(oA - 64) * CIN;

  floatx4 acc[4];
#pragma unroll
  for (int b2 = 0; b2 < 4; ++b2) acc[b2] = (floatx4){0.f, 0.f, 0.f, 0.f};

#pragma unroll
  for (int ks = 0; ks < 8; ++ks) {
    const short8 af = mk_bf16x8(Arow + ks * 32 + 8 * quad);
#pragma unroll
    for (int b2 = 0; b2 < 4; ++b2) {
      const short8 bf = *(const short8*)&xbT[b2 * 16 + l15][ks * 32 + 8 * quad];
      acc[b2] = __builtin_amdgcn_mfma_f32_16x16x32_bf16(af, bf, acc[b2], 0, 0, 0);
    }
  }

  // Epilogue.  C-layout: col = l15 (n within subtile), row = 4*quad + r (o).
#pragma unroll
  for (int b2 = 0; b2 < 4; ++b2) {
    const int n = n0 + b2 * 16 + l15;
#pragma unroll
    for (int r = 0; r < 4; ++r) {
      const int o = obase + 4 * quad + r;
      const float val = acc[b2][r];
      if (oc == 0) {
        if (o < 32) qT[(size_t)n * DQ + o]        = f2bf((val + bq[o]) * LOG2E);
        else        kT[(size_t)n * DQ + (o - 32)] = f2bf(val + bk[o - 32]);
      } else        vG[(size_t)(o - 64) * N + n]  = f2bf(val + bv[o - 64]);
    }
  }
}

// ---------------------------------------------------------------------------
// Kernel 2: flash attention.  R10: NBLK 64 -> 128 (V-traffic halving).
// Evidence: attn invariant at ~111.5 us across 5 schedule variants =>
// traffic-bound, and the uncounted traffic is V: each of 144 n-sweeps
// re-reads the full 4.7 MB vG from L3 (679 MB total, +86 MB K = 6.9 TB/s
// cache-side -- at the Infinity Cache ceiling).  Fix: 128 n per block,
// 8 waves; wave w = (wc = w&3, nh = w>>2).  Waves sharing wc issue
// IDENTICAL V/K addresses for the two n-halves -> unique-line traffic
// halves (V 679->340 MB, K 86->43 MB).  Per-wave registers and per-iter
// instruction mix byte-identical to R9 (76+64 regs, 4 QK + 16 exp + 32 PV)
// -- clean A/B of {traffic/2 + 8-wave barrier} vs R9.  Opart layout
// unchanged: block writes nt = 2*ntp + nh.
// ---------------------------------------------------------------------------
__global__ __launch_bounds__(512, 3) void attn_kernel(
    const ushort_t* __restrict__ qT, const ushort_t* __restrict__ kT,
    const ushort_t* __restrict__ vG,
    ushort_t* __restrict__ Opart, float* __restrict__ lpart,
    int base, int rem)
{
  __shared__ ushort_t Pb[2][2][64][72]; // [buf][n-half][row][m]  36.9 KB

  const int t = threadIdx.x;
  const int w = t >> 6;                 // 0..7
  const int lane = t & 63;
  const int quad = lane >> 4;
  const int l15 = lane & 15;
  const int wc = w & 3;                 // c-strip AND QK n-16-block
  const int nh = w >> 2;                // n-half
  const int ntp = blockIdx.x;           // 0..71 (128-n tiles)
  const int s  = blockIdx.y;
  const int n0 = ntp * 128;
  const int sliceIters = base + (s < rem ? 1 : 0);
  const int it0 = s * base + (s < rem ? s : rem);
  const int mbase = it0 * 64;
  const int cw = wc * 64;

  // QK A-operand: Q rows n = n0 + nh*64 + wc*16 + l15
  const short8 aq = *(const short8*)(
      qT + (size_t)(n0 + nh * 64 + wc * 16 + l15) * DQ + 8 * quad);

  floatx4 acc[4][4];                    // [a2 = c 16-block][b2 = n 16-block]
#pragma unroll
  for (int a2 = 0; a2 < 4; ++a2)
#pragma unroll
    for (int b2 = 0; b2 < 4; ++b2)
      acc[a2][b2] = (floatx4){0.f, 0.f, 0.f, 0.f};
  float lsum[4] = {0.f, 0.f, 0.f, 0.f};
  const floatx4 z4 = {0.f, 0.f, 0.f, 0.f};

  // K/V pointers: INDEPENDENT of nh -> the two waves sharing wc load
  // identical lines (the amortization).
  const ushort_t* kRow  = kT + (size_t)(mbase + l15) * DQ + 8 * quad;
  const ushort_t* vRow0 = vG + (size_t)(cw +  0 + l15) * N + mbase + 8 * quad;
  const ushort_t* vRow1 = vG + (size_t)(cw + 16 + l15) * N + mbase + 8 * quad;
  const ushort_t* vRow2 = vG + (size_t)(cw + 32 + l15) * N + mbase + 8 * quad;
  const ushort_t* vRow3 = vG + (size_t)(cw + 48 + l15) * N + mbase + 8 * quad;

  for (int it = 0; it < sliceIters; ++it) {
    const short8 kb0 = *(const short8*)(kRow);
    const short8 kb1 = *(const short8*)(kRow + 16 * DQ);
    const short8 kb2 = *(const short8*)(kRow + 32 * DQ);
    const short8 kb3 = *(const short8*)(kRow + 48 * DQ);
    kRow += 64 * DQ;
    const short8 av00 = *(const short8*)(vRow0);
    const short8 av01 = *(const short8*)(vRow0 + 32);
    const short8 av10 = *(const short8*)(vRow1);
    const short8 av11 = *(const short8*)(vRow1 + 32);
    const short8 av20 = *(const short8*)(vRow2);
    const short8 av21 = *(const short8*)(vRow2 + 32);
    const short8 av30 = *(const short8*)(vRow3);
    const short8 av31 = *(const short8*)(vRow3 + 32);
    vRow0 += 64; vRow1 += 64; vRow2 += 64; vRow3 += 64;

    // QK: this wave's 16 n x 64 m scores (for its n-half).
    floatx4 s0 = __builtin_amdgcn_mfma_f32_16x16x32_bf16(aq, kb0, z4, 0, 0, 0);
    floatx4 s1 = __builtin_amdgcn_mfma_f32_16x16x32_bf16(aq, kb1, z4, 0, 0, 0);
    floatx4 s2 = __builtin_amdgcn_mfma_f32_16x16x32_bf16(aq, kb2, z4, 0, 0, 0);
    floatx4 s3 = __builtin_amdgcn_mfma_f32_16x16x32_bf16(aq, kb3, z4, 0, 0, 0);

    ushort_t* pb = &Pb[it & 1][nh][0][0];
#pragma unroll
    for (int r = 0; r < 4; ++r) {
      const int row = 16 * wc + 4 * quad + r;
      float p0 = exp2f(s0[r]);
      float p1 = exp2f(s1[r]);
      float p2 = exp2f(s2[r]);
      float p3 = exp2f(s3[r]);
      lsum[r] += (p0 + p1) + (p2 + p3);
      pb[row * 72 +      l15] = f2bf_fast(p0);
      pb[row * 72 + 16 + l15] = f2bf_fast(p1);
      pb[row * 72 + 32 + l15] = f2bf_fast(p2);
      pb[row * 72 + 48 + l15] = f2bf_fast(p3);
    }

    barrier_lds_only();   // LDS drain + rendezvous; V loads stay in flight

    __builtin_amdgcn_s_setprio(1);
#pragma unroll
    for (int b2 = 0; b2 < 4; ++b2) {
      const ushort_t* prow = &Pb[it & 1][nh][b2 * 16 + l15][0];
      const short8 pfLo = *(const short8*)(prow + 8 * quad);        // m 0..31
      const short8 pfHi = *(const short8*)(prow + 32 + 8 * quad);   // m 32..63
      acc[0][b2] = __builtin_amdgcn_mfma_f32_16x16x32_bf16(av00, pfLo, acc[0][b2], 0, 0, 0);
      acc[1][b2] = __builtin_amdgcn_mfma_f32_16x16x32_bf16(av10, pfLo, acc[1][b2], 0, 0, 0);
      acc[2][b2] = __builtin_amdgcn_mfma_f32_16x16x32_bf16(av20, pfLo, acc[2][b2], 0, 0, 0);
      acc[3][b2] = __builtin_amdgcn_mfma_f32_16x16x32_bf16(av30, pfLo, acc[3][b2], 0, 0, 0);
      acc[0][b2] = __builtin_amdgcn_mfma_f32_16x16x32_bf16(av01, pfHi, acc[0][b2], 0, 0, 0);
      acc[1][b2] = __builtin_amdgcn_mfma_f32_16x16x32_bf16(av11, pfHi, acc[1][b2], 0, 0, 0);
      acc[2][b2] = __builtin_amdgcn_mfma_f32_16x16x32_bf16(av21, pfHi, acc[2][b2], 0, 0, 0);
      acc[3][b2] = __builtin_amdgcn_mfma_f32_16x16x32_bf16(av31, pfHi, acc[3][b2], 0, 0, 0);
    }
    __builtin_amdgcn_s_setprio(0);
    // WAR on Pb[it&1] safe: each wave's reads drain at its own lgkmcnt(0)
    // before it passes barrier(it+1); rewrites happen after barrier(it+1).
  }

#pragma unroll
  for (int r = 0; r < 4; ++r) {
    float v = lsum[r];
    v += __shfl_xor(v, 1);
    v += __shfl_xor(v, 2);
    v += __shfl_xor(v, 4);
    v += __shfl_xor(v, 8);
    lsum[r] = v;
  }
  if (l15 == 0) {
#pragma unroll
    for (int r = 0; r < 4; ++r)
      lpart[(size_t)s * N + n0 + nh * 64 + 16 * wc + 4 * quad + r] = lsum[r];
  }

  // Opart: nt = 2*ntp + nh keeps the layout identical to the 64-n scheme.
  const size_t basep = ((size_t)s * NT + 2 * ntp + nh) * 256;
#pragma unroll
  for (int a2 = 0; a2 < 4; ++a2)
#pragma unroll
    for (int b2 = 0; b2 < 4; ++b2)
#pragma unroll
      for (int r = 0; r < 4; ++r) {
        const int c  = cw + a2 * 16 + 4 * quad + r;
        const int nl = b2 * 16 + l15;
        Opart[(basep + c) * 64 + nl] = f2bf(acc[a2][b2][r]);
      }
}

// ---------------------------------------------------------------------------
// Kernel 3: fused combine + gate-exp.  UNCHANGED (control).
// ---------------------------------------------------------------------------
template<int NSL>
__global__ __launch_bounds__(1024) void cco_kernel(
    const ushort_t* __restrict__ Opart, const float* __restrict__ lpart,
    float* __restrict__ e_buf, float* __restrict__ sumExp)
{
  const int nt = blockIdx.x;
  const int t = threadIdx.x;
  const int n = t & 63, ci = t >> 6;   // ci in [0,16)
  float mx = -3.4e38f, sm = 0.f;
#pragma unroll
  for (int k = 0; k < 16; ++k) {
    const int c = ci * 16 + k;
    float val = 0.f;
#pragma unroll
    for (int s2 = 0; s2 < NSL; ++s2)
      val += bf2f(Opart[(((size_t)s2 * NT + nt) * 256 + c) * 64 + n]);
    mx = fmaxf(mx, val);
    sm += val;
  }
  __shared__ float rmx[16][64], rsm[16][64];
  rmx[ci][n] = mx; rsm[ci][n] = sm;
  __syncthreads();
  if (t < 64) {
    float m = rmx[0][t], s = rsm[0][t];
#pragma unroll
    for (int g = 1; g < 16; ++g) { m = fmaxf(m, rmx[g][t]); s += rsm[g][t]; }
    float l = 0.f;
#pragma unroll
    for (int s3 = 0; s3 < NSL; ++s3) l += lpart[(size_t)s3 * N + nt * 64 + t];
    const float oc = (m + s * (1.0f / 256.0f)) / l;
    const float ev = exp2f(oc * (0.0625f * LOG2E));
    e_buf[nt * 64 + t] = ev;
    float vs = ev;
    vs += __shfl_xor(vs, 1);  vs += __shfl_xor(vs, 2);
    vs += __shfl_xor(vs, 4);  vs += __shfl_xor(vs, 8);
    vs += __shfl_xor(vs, 16); vs += __shfl_xor(vs, 32);
    if (t == 0) atomicAdd(sumExp, vs);
  }
}

// ---------------------------------------------------------------------------
// Kernel 4: final 1x1 conv via bf16 MFMA + fp32 epilogue.  UNCHANGED
// (control, R5 form).
// ---------------------------------------------------------------------------
__global__ __launch_bounds__(256) void final_mfma(
    const float* __restrict__ x, const float* __restrict__ W6,
    const float* __restrict__ b6, const float* __restrict__ gamma,
    const float* __restrict__ e_buf, const float* __restrict__ sumExp,
    float* __restrict__ out)
{
  __shared__ ushort_t xbT[64][XBT_STRIDE];
  const int t = threadIdx.x;
  const int n0 = blockIdx.x * 64;
  const int w = t >> 6, lane = t & 63;
  const int quad = lane >> 4, l15 = lane & 15;

  stage_x_tile(x, n0, t, xbT);
  __syncthreads();

  const int obase = blockIdx.y * 64 + w * 16;
  const float* Arow = W6 + (size_t)(obase + l15) * CIN;

  floatx4 acc[4];
#pragma unroll
  for (int b2 = 0; b2 < 4; ++b2) acc[b2] = (floatx4){0.f, 0.f, 0.f, 0.f};

#pragma unroll
  for (int ks = 0; ks < 8; ++ks) {
    const short8 af = mk_bf16x8(Arow + ks * 32 + 8 * quad);
#pragma unroll
    for (int b2 = 0; b2 < 4; ++b2) {
      const short8 bf = *(const short8*)&xbT[b2 * 16 + l15][ks * 32 + 8 * quad];
      acc[b2] = __builtin_amdgcn_mfma_f32_16x16x32_bf16(af, bf, acc[b2], 0, 0, 0);
    }
  }

  const float g1 = 1.0f + gamma[0];
  const float inv = 1.0f / sumExp[0];
#pragma unroll
  for (int b2 = 0; b2 < 4; ++b2) {
    const int n = n0 + b2 * 16 + l15;
    const float xc = e_buf[n] * inv;
#pragma unroll
    for (int r = 0; r < 4; ++r) {
      const int o = obase + 4 * quad + r;
      const float xv = x[(size_t)o * N + n];
      out[(size_t)o * N + n] = xv + g1 * (xc * acc[b2][r] + b6[o]);
    }
  }
}

// ---------------------------------------------------------------------------
extern "C" void kernel_launch(void* const* d_in, const int* in_sizes, int n_in,
                              void* d_out, int out_size, void* d_ws, size_t ws_size,
                              hipStream_t stream)
{
  const float* x     = (const float*)d_in[0];
  const float* Wq    = (const float*)d_in[1];
  const float* bq    = (const float*)d_in[2];
  const float* Wk    = (const float*)d_in[3];
  const float* bk    = (const float*)d_in[4];
  const float* Wv    = (const float*)d_in[5];
  const float* bv    = (const float*)d_in[6];
  const float* W6    = (const float*)d_in[7];
  const float* b6    = (const float*)d_in[8];
  const float* gamma = (const float*)d_in[9];
  float* out = (float*)d_out;

  const size_t fixed = (size_t)N * DQ * 2 * 2        // qT,kT
                     + (size_t)CIN * N * 2            // vG
                     + (size_t)N * 4                  // e_buf
                     + 256;                           // sumExp (+pad)
  int nsl = 7;
  size_t need = fixed + (size_t)nsl * NT * 256 * 64 * 2 + (size_t)nsl * N * 4;
  if (ws_size < need) nsl = 4;
  const int totIters = N / 64;                        // 144 (64-m tiles)
  const int base = totIters / nsl;
  const int rem  = totIters % nsl;

  char* ws = (char*)d_ws;
  const size_t OFF_QT = 0;
  const size_t OFF_KT = OFF_QT + (size_t)N * DQ * 2;
  const size_t OFF_V  = OFF_KT + (size_t)N * DQ * 2;
  const size_t OFF_OP = OFF_V  + (size_t)CIN * N * 2;
  const size_t OFF_LP = OFF_OP + (size_t)nsl * NT * 256 * 64 * 2;
  const size_t OFF_EB = OFF_LP + (size_t)nsl * N * 4;
  const size_t OFF_SE = OFF_EB + (size_t)N * 4;

  ushort_t* qT     = (ushort_t*)(ws + OFF_QT);
  ushort_t* kT     = (ushort_t*)(ws + OFF_KT);
  ushort_t* vG     = (ushort_t*)(ws + OFF_V);
  ushort_t* Opart  = (ushort_t*)(ws + OFF_OP);
  float*    lpart  = (float*)(ws + OFF_LP);
  float*    e_buf  = (float*)(ws + OFF_EB);
  float*    sumExp = (float*)(ws + OFF_SE);

  qkv_mfma<<<dim3(NT, 5), 256, 0, stream>>>(x, Wq, bq, Wk, bk, Wv, bv, qT, kT, vG, sumExp);
  attn_kernel<<<dim3(NT / 2, nsl), 512, 0, stream>>>(qT, kT, vG, Opart, lpart, base, rem);
  if (nsl == 7) cco_kernel<7><<<NT, 1024, 0, stream>>>(Opart, lpart, e_buf, sumExp);
  else          cco_kernel<4><<<NT, 1024, 0, stream>>>(Opart, lpart, e_buf, sumExp);
  final_mfma<<<dim3(NT, 4), 256, 0, stream>>>(x, W6, b6, gamma, e_buf, sumExp, out);
}

// Round 11
// 211.477 us; speedup vs baseline: 1.0297x; 1.0297x over previous
//
#include <hip/hip_runtime.h>

#define N 9216
#define CIN 256
#define DQ 32
#define NT 144                      // N / 64
#define LOG2E 1.44269504088896340736f

typedef short short8 __attribute__((ext_vector_type(8)));   // 8 bf16 in 4 VGPRs
typedef float floatx4 __attribute__((ext_vector_type(4)));
typedef unsigned short ushort_t;

__device__ __forceinline__ ushort_t f2bf(float f) {
  union { float f; unsigned u; } a; a.f = f;
  unsigned u = a.u;
  u += 0x7fffu + ((u >> 16) & 1u);   // round-to-nearest-even
  return (ushort_t)(u >> 16);
}
// cheap round-to-nearest: 2 VALU ops instead of 5.
__device__ __forceinline__ ushort_t f2bf_fast(float f) {
  union { float f; unsigned u; } a; a.f = f;
  return (ushort_t)((a.u + 0x8000u) >> 16);
}
__device__ __forceinline__ float bf2f(ushort_t h) {
  union { unsigned u; float f; } a; a.u = ((unsigned)h) << 16;
  return a.f;
}
// pack two floats -> one uint of 2 bf16 (lo = c, hi = c1)
__device__ __forceinline__ unsigned pack2(float lo, float hi) {
  return ((unsigned)f2bf_fast(hi) << 16) | (unsigned)f2bf_fast(lo);
}

// LDS-visibility-only barrier: drains lgkmcnt (LDS) but leaves global
// register loads (vmcnt) in flight across the rendezvous.
__device__ __forceinline__ void barrier_lds_only() {
  asm volatile("s_waitcnt lgkmcnt(0)" ::: "memory");
  __builtin_amdgcn_s_barrier();
  asm volatile("" ::: "memory");
}

// ---------------------------------------------------------------------------
// Shared staging: x tile (256 c x 64 n) -> LDS bf16 xbT[n][k=c].
// ---------------------------------------------------------------------------
#define XBT_STRIDE 264   // ushorts per row (256 + 8 pad); 132 uints

__device__ __forceinline__ void stage_x_tile(
    const float* __restrict__ x, int n0, int t, ushort_t (*xbT)[XBT_STRIDE])
{
  const int p = t & 31, ng = t >> 5;          // ng in [0,8)
  unsigned* base = (unsigned*)&xbT[0][0] + (size_t)(ng * 8) * 132;
#pragma unroll
  for (int cc = 0; cc < 4; ++cc) {
    const int c = cc * 64 + 2 * p;
    const float* r0 = x + (size_t)c * N + n0 + ng * 8;
    const float* r1 = r0 + N;
    float4 a0 = *(const float4*)(r0);
    float4 a1 = *(const float4*)(r0 + 4);
    float4 b0 = *(const float4*)(r1);
    float4 b1 = *(const float4*)(r1 + 4);
    unsigned* d = base + (cc * 32 + p);
    d[0 * 132] = pack2(a0.x, b0.x);
    d[1 * 132] = pack2(a0.y, b0.y);
    d[2 * 132] = pack2(a0.z, b0.z);
    d[3 * 132] = pack2(a0.w, b0.w);
    d[4 * 132] = pack2(a1.x, b1.x);
    d[5 * 132] = pack2(a1.y, b1.y);
    d[6 * 132] = pack2(a1.z, b1.z);
    d[7 * 132] = pack2(a1.w, b1.w);
  }
}

// ---------------------------------------------------------------------------
// Kernel 0: one-time fp32 -> bf16 conversion of all W matrices (R11: the
// un-confounded half of R6 -- grids below stay (144,5)/(144,4)).  Same
// f2bf_fast rounding as the old per-use mk_bf16x8 => A-frags bit-identical.
// Wb layout (ushort elems): Wq @0 (8192), Wk @8192 (8192), Wv @16384
// (65536), W6 @81920 (65536).
// ---------------------------------------------------------------------------
__global__ __launch_bounds__(256) void wconv_kernel(
    const float* __restrict__ Wq, const float* __restrict__ Wk,
    const float* __restrict__ Wv, const float* __restrict__ W6,
    ushort_t* __restrict__ Wb)
{
  const int idx = blockIdx.x * 256 + threadIdx.x;   // 0..36863
  const int base = idx * 4;
  float4 f;
  if      (base <  8192) f = *(const float4*)(Wq + base);
  else if (base < 16384) f = *(const float4*)(Wk + base - 8192);
  else if (base < 81920) f = *(const float4*)(Wv + base - 16384);
  else                   f = *(const float4*)(W6 + base - 81920);
  uint2 o;
  o.x = pack2(f.x, f.y);
  o.y = pack2(f.z, f.w);
  *(uint2*)(Wb + base) = o;
}

// ---------------------------------------------------------------------------
// Kernel 1: q/k/v projections via bf16 MFMA.  R11: grid (144,5) KEPT
// (R6's fold to 144 blocks starved CUs, -13 us); only change vs R5 form:
// A-frags are 16B L2-hot short8 loads from pre-converted Wb instead of
// 8 fp32 loads + 12 pack-VALU per frag.
// ---------------------------------------------------------------------------
__global__ __launch_bounds__(256) void qkv_mfma(
    const float* __restrict__ x, const ushort_t* __restrict__ Wb,
    const float* __restrict__ bq, const float* __restrict__ bk,
    const float* __restrict__ bv,
    ushort_t* __restrict__ qT, ushort_t* __restrict__ kT,
    ushort_t* __restrict__ vG, float* __restrict__ sumExp)
{
  if (blockIdx.x == 0 && blockIdx.y == 0 && threadIdx.x == 0) *sumExp = 0.f;

  __shared__ ushort_t xbT[64][XBT_STRIDE];
  const int t = threadIdx.x;
  const int n0 = blockIdx.x * 64;
  const int oc = blockIdx.y;                 // 0: q(32)+k(32); 1..4: v
  const int w = t >> 6, lane = t & 63;
  const int quad = lane >> 4, l15 = lane & 15;

  stage_x_tile(x, n0, t, xbT);
  __syncthreads();

  const int obase = oc * 64 + w * 16;
  const ushort_t* Arow;
  if (oc == 0) Arow = (obase < 32) ? (Wb + (size_t)(obase + l15) * CIN)
                                   : (Wb + 8192 + (size_t)(obase - 32 + l15) * CIN);
  else         Arow = Wb + 16384 + (size_t)(obase - 64 + l15) * CIN;

  floatx4 acc[4];
#pragma unroll
  for (int b2 = 0; b2 < 4; ++b2) acc[b2] = (floatx4){0.f, 0.f, 0.f, 0.f};

#pragma unroll
  for (int ks = 0; ks < 8; ++ks) {
    const short8 af = *(const short8*)(Arow + ks * 32 + 8 * quad);
#pragma unroll
    for (int b2 = 0; b2 < 4; ++b2) {
      const short8 bf = *(const short8*)&xbT[b2 * 16 + l15][ks * 32 + 8 * quad];
      acc[b2] = __builtin_amdgcn_mfma_f32_16x16x32_bf16(af, bf, acc[b2], 0, 0, 0);
    }
  }

  // Epilogue.  C-layout: col = l15 (n within subtile), row = 4*quad + r (o).
#pragma unroll
  for (int b2 = 0; b2 < 4; ++b2) {
    const int n = n0 + b2 * 16 + l15;
#pragma unroll
    for (int r = 0; r < 4; ++r) {
      const int o = obase + 4 * quad + r;
      const float val = acc[b2][r];
      if (oc == 0) {
        if (o < 32) qT[(size_t)n * DQ + o]        = f2bf((val + bq[o]) * LOG2E);
        else        kT[(size_t)n * DQ + (o - 32)] = f2bf(val + bk[o - 32]);
      } else        vG[(size_t)(o - 64) * N + n]  = f2bf(val + bv[o - 64]);
    }
  }
}

// ---------------------------------------------------------------------------
// Kernel 2: flash attention.  UNCHANGED from R9 (control; 111.4 us --
// structural floor after 6 null variants: schedule, barrier count/semantics,
// traffic dedup all invariant at 111-115).
// ---------------------------------------------------------------------------
__global__ __launch_bounds__(256, 3) void attn_kernel(
    const ushort_t* __restrict__ qT, const ushort_t* __restrict__ kT,
    const ushort_t* __restrict__ vG,
    ushort_t* __restrict__ Opart, float* __restrict__ lpart,
    int base, int rem)
{
  __shared__ ushort_t Pb[2][64][72];    // double-buffered P tile (64n x 64m)

  const int t = threadIdx.x;
  const int w = t >> 6;
  const int lane = t & 63;
  const int quad = lane >> 4;
  const int l15 = lane & 15;
  const int nt = blockIdx.x;
  const int s  = blockIdx.y;
  const int n0 = nt * 64;
  const int sliceIters = base + (s < rem ? 1 : 0);
  const int it0 = s * base + (s < rem ? s : rem);
  const int mbase = it0 * 64;
  const int cw = w * 64;

  const short8 aq =
      *(const short8*)(qT + (size_t)(n0 + 16 * w + l15) * DQ + 8 * quad);

  floatx4 acc[4][4];                    // [a2 = c 16-block][b2 = n 16-block]
#pragma unroll
  for (int a2 = 0; a2 < 4; ++a2)
#pragma unroll
    for (int b2 = 0; b2 < 4; ++b2)
      acc[a2][b2] = (floatx4){0.f, 0.f, 0.f, 0.f};
  float lsum[4] = {0.f, 0.f, 0.f, 0.f};
  const floatx4 z4 = {0.f, 0.f, 0.f, 0.f};

  const ushort_t* kRow  = kT + (size_t)(mbase + l15) * DQ + 8 * quad;
  const ushort_t* vRow0 = vG + (size_t)(cw +  0 + l15) * N + mbase + 8 * quad;
  const ushort_t* vRow1 = vG + (size_t)(cw + 16 + l15) * N + mbase + 8 * quad;
  const ushort_t* vRow2 = vG + (size_t)(cw + 32 + l15) * N + mbase + 8 * quad;
  const ushort_t* vRow3 = vG + (size_t)(cw + 48 + l15) * N + mbase + 8 * quad;

  for (int it = 0; it < sliceIters; ++it) {
    // K rows for m-blocks 0..3 (QK needs them soonest).
    const short8 kb0 = *(const short8*)(kRow);
    const short8 kb1 = *(const short8*)(kRow + 16 * DQ);
    const short8 kb2 = *(const short8*)(kRow + 32 * DQ);
    const short8 kb3 = *(const short8*)(kRow + 48 * DQ);
    kRow += 64 * DQ;
    // V: 4 c-blocks x 2 m-halves.  Issued pre-barrier; waited at PV only.
    const short8 av00 = *(const short8*)(vRow0);
    const short8 av01 = *(const short8*)(vRow0 + 32);
    const short8 av10 = *(const short8*)(vRow1);
    const short8 av11 = *(const short8*)(vRow1 + 32);
    const short8 av20 = *(const short8*)(vRow2);
    const short8 av21 = *(const short8*)(vRow2 + 32);
    const short8 av30 = *(const short8*)(vRow3);
    const short8 av31 = *(const short8*)(vRow3 + 32);
    vRow0 += 64; vRow1 += 64; vRow2 += 64; vRow3 += 64;

    // QK: this wave's 16 n x 64 m scores.
    floatx4 s0 = __builtin_amdgcn_mfma_f32_16x16x32_bf16(aq, kb0, z4, 0, 0, 0);
    floatx4 s1 = __builtin_amdgcn_mfma_f32_16x16x32_bf16(aq, kb1, z4, 0, 0, 0);
    floatx4 s2 = __builtin_amdgcn_mfma_f32_16x16x32_bf16(aq, kb2, z4, 0, 0, 0);
    floatx4 s3 = __builtin_amdgcn_mfma_f32_16x16x32_bf16(aq, kb3, z4, 0, 0, 0);

    ushort_t* pb = &Pb[it & 1][0][0];
#pragma unroll
    for (int r = 0; r < 4; ++r) {
      const int row = 16 * w + 4 * quad + r;
      float p0 = exp2f(s0[r]);
      float p1 = exp2f(s1[r]);
      float p2 = exp2f(s2[r]);
      float p3 = exp2f(s3[r]);
      lsum[r] += (p0 + p1) + (p2 + p3);
      pb[row * 72 +      l15] = f2bf_fast(p0);
      pb[row * 72 + 16 + l15] = f2bf_fast(p1);
      pb[row * 72 + 32 + l15] = f2bf_fast(p2);
      pb[row * 72 + 48 + l15] = f2bf_fast(p3);
    }

    barrier_lds_only();   // LDS drain + rendezvous; V loads stay in flight

    __builtin_amdgcn_s_setprio(1);
#pragma unroll
    for (int b2 = 0; b2 < 4; ++b2) {
      const ushort_t* prow = &Pb[it & 1][b2 * 16 + l15][0];
      const short8 pfLo = *(const short8*)(prow + 8 * quad);        // m 0..31
      const short8 pfHi = *(const short8*)(prow + 32 + 8 * quad);   // m 32..63
      acc[0][b2] = __builtin_amdgcn_mfma_f32_16x16x32_bf16(av00, pfLo, acc[0][b2], 0, 0, 0);
      acc[1][b2] = __builtin_amdgcn_mfma_f32_16x16x32_bf16(av10, pfLo, acc[1][b2], 0, 0, 0);
      acc[2][b2] = __builtin_amdgcn_mfma_f32_16x16x32_bf16(av20, pfLo, acc[2][b2], 0, 0, 0);
      acc[3][b2] = __builtin_amdgcn_mfma_f32_16x16x32_bf16(av30, pfLo, acc[3][b2], 0, 0, 0);
      acc[0][b2] = __builtin_amdgcn_mfma_f32_16x16x32_bf16(av01, pfHi, acc[0][b2], 0, 0, 0);
      acc[1][b2] = __builtin_amdgcn_mfma_f32_16x16x32_bf16(av11, pfHi, acc[1][b2], 0, 0, 0);
      acc[2][b2] = __builtin_amdgcn_mfma_f32_16x16x32_bf16(av21, pfHi, acc[2][b2], 0, 0, 0);
      acc[3][b2] = __builtin_amdgcn_mfma_f32_16x16x32_bf16(av31, pfHi, acc[3][b2], 0, 0, 0);
    }
    __builtin_amdgcn_s_setprio(0);
    // WAR on Pb[it&1] safe: each wave's reads drain at its own lgkmcnt(0)
    // before it passes barrier(it+1); rewrites happen after barrier(it+1).
  }

#pragma unroll
  for (int r = 0; r < 4; ++r) {
    float v = lsum[r];
    v += __shfl_xor(v, 1);
    v += __shfl_xor(v, 2);
    v += __shfl_xor(v, 4);
    v += __shfl_xor(v, 8);
    lsum[r] = v;
  }
  if (l15 == 0) {
#pragma unroll
    for (int r = 0; r < 4; ++r)
      lpart[(size_t)s * N + n0 + 16 * w + 4 * quad + r] = lsum[r];
  }

  const size_t basep = ((size_t)s * NT + nt) * 256;
#pragma unroll
  for (int a2 = 0; a2 < 4; ++a2)
#pragma unroll
    for (int b2 = 0; b2 < 4; ++b2)
#pragma unroll
      for (int r = 0; r < 4; ++r) {
        const int c  = cw + a2 * 16 + 4 * quad + r;
        const int nl = b2 * 16 + l15;
        Opart[(basep + c) * 64 + nl] = f2bf(acc[a2][b2][r]);
      }
}

// ---------------------------------------------------------------------------
// Kernel 3: fused combine + gate-exp.  UNCHANGED (control).
// ---------------------------------------------------------------------------
template<int NSL>
__global__ __launch_bounds__(1024) void cco_kernel(
    const ushort_t* __restrict__ Opart, const float* __restrict__ lpart,
    float* __restrict__ e_buf, float* __restrict__ sumExp)
{
  const int nt = blockIdx.x;
  const int t = threadIdx.x;
  const int n = t & 63, ci = t >> 6;   // ci in [0,16)
  float mx = -3.4e38f, sm = 0.f;
#pragma unroll
  for (int k = 0; k < 16; ++k) {
    const int c = ci * 16 + k;
    float val = 0.f;
#pragma unroll
    for (int s2 = 0; s2 < NSL; ++s2)
      val += bf2f(Opart[(((size_t)s2 * NT + nt) * 256 + c) * 64 + n]);
    mx = fmaxf(mx, val);
    sm += val;
  }
  __shared__ float rmx[16][64], rsm[16][64];
  rmx[ci][n] = mx; rsm[ci][n] = sm;
  __syncthreads();
  if (t < 64) {
    float m = rmx[0][t], s = rsm[0][t];
#pragma unroll
    for (int g = 1; g < 16; ++g) { m = fmaxf(m, rmx[g][t]); s += rsm[g][t]; }
    float l = 0.f;
#pragma unroll
    for (int s3 = 0; s3 < NSL; ++s3) l += lpart[(size_t)s3 * N + nt * 64 + t];
    const float oc = (m + s * (1.0f / 256.0f)) / l;
    const float ev = exp2f(oc * (0.0625f * LOG2E));
    e_buf[nt * 64 + t] = ev;
    float vs = ev;
    vs += __shfl_xor(vs, 1);  vs += __shfl_xor(vs, 2);
    vs += __shfl_xor(vs, 4);  vs += __shfl_xor(vs, 8);
    vs += __shfl_xor(vs, 16); vs += __shfl_xor(vs, 32);
    if (t == 0) atomicAdd(sumExp, vs);
  }
}

// ---------------------------------------------------------------------------
// Kernel 4: final 1x1 conv via bf16 MFMA + fp32 epilogue.  R11: grid
// (144,4) KEPT; only change vs R5 form: A-frags from pre-converted W6b.
// ---------------------------------------------------------------------------
__global__ __launch_bounds__(256) void final_mfma(
    const float* __restrict__ x, const ushort_t* __restrict__ W6b,
    const float* __restrict__ b6, const float* __restrict__ gamma,
    const float* __restrict__ e_buf, const float* __restrict__ sumExp,
    float* __restrict__ out)
{
  __shared__ ushort_t xbT[64][XBT_STRIDE];
  const int t = threadIdx.x;
  const int n0 = blockIdx.x * 64;
  const int w = t >> 6, lane = t & 63;
  const int quad = lane >> 4, l15 = lane & 15;

  stage_x_tile(x, n0, t, xbT);
  __syncthreads();

  const int obase = blockIdx.y * 64 + w * 16;
  const ushort_t* Arow = W6b + (size_t)(obase + l15) * CIN;

  floatx4 acc[4];
#pragma unroll
  for (int b2 = 0; b2 < 4; ++b2) acc[b2] = (floatx4){0.f, 0.f, 0.f, 0.f};

#pragma unroll
  for (int ks = 0; ks < 8; ++ks) {
    const short8 af = *(const short8*)(Arow + ks * 32 + 8 * quad);
#pragma unroll
    for (int b2 = 0; b2 < 4; ++b2) {
      const short8 bf = *(const short8*)&xbT[b2 * 16 + l15][ks * 32 + 8 * quad];
      acc[b2] = __builtin_amdgcn_mfma_f32_16x16x32_bf16(af, bf, acc[b2], 0, 0, 0);
    }
  }

  const float g1 = 1.0f + gamma[0];
  const float inv = 1.0f / sumExp[0];
#pragma unroll
  for (int b2 = 0; b2 < 4; ++b2) {
    const int n = n0 + b2 * 16 + l15;
    const float xc = e_buf[n] * inv;
#pragma unroll
    for (int r = 0; r < 4; ++r) {
      const int o = obase + 4 * quad + r;
      const float xv = x[(size_t)o * N + n];
      out[(size_t)o * N + n] = xv + g1 * (xc * acc[b2][r] + b6[o]);
    }
  }
}

// ---------------------------------------------------------------------------
extern "C" void kernel_launch(void* const* d_in, const int* in_sizes, int n_in,
                              void* d_out, int out_size, void* d_ws, size_t ws_size,
                              hipStream_t stream)
{
  const float* x     = (const float*)d_in[0];
  const float* Wq    = (const float*)d_in[1];
  const float* bq    = (const float*)d_in[2];
  const float* Wk    = (const float*)d_in[3];
  const float* bk    = (const float*)d_in[4];
  const float* Wv    = (const float*)d_in[5];
  const float* bv    = (const float*)d_in[6];
  const float* W6    = (const float*)d_in[7];
  const float* b6    = (const float*)d_in[8];
  const float* gamma = (const float*)d_in[9];
  float* out = (float*)d_out;

  const size_t WB_BYTES = (size_t)(8192 + 8192 + 65536 + 65536) * 2;  // 294912
  const size_t fixed = WB_BYTES
                     + (size_t)N * DQ * 2 * 2        // qT,kT
                     + (size_t)CIN * N * 2            // vG
                     + (size_t)N * 4                  // e_buf
                     + 256;                           // sumExp (+pad)
  int nsl = 7;
  size_t need = fixed + (size_t)nsl * NT * 256 * 64 * 2 + (size_t)nsl * N * 4;
  if (ws_size < need) nsl = 4;
  const int totIters = N / 64;                        // 144 (64-m tiles)
  const int base = totIters / nsl;
  const int rem  = totIters % nsl;

  char* ws = (char*)d_ws;
  const size_t OFF_WB = 0;
  const size_t OFF_QT = OFF_WB + WB_BYTES;
  const size_t OFF_KT = OFF_QT + (size_t)N * DQ * 2;
  const size_t OFF_V  = OFF_KT + (size_t)N * DQ * 2;
  const size_t OFF_OP = OFF_V  + (size_t)CIN * N * 2;
  const size_t OFF_LP = OFF_OP + (size_t)nsl * NT * 256 * 64 * 2;
  const size_t OFF_EB = OFF_LP + (size_t)nsl * N * 4;
  const size_t OFF_SE = OFF_EB + (size_t)N * 4;

  ushort_t* Wb     = (ushort_t*)(ws + OFF_WB);
  ushort_t* qT     = (ushort_t*)(ws + OFF_QT);
  ushort_t* kT     = (ushort_t*)(ws + OFF_KT);
  ushort_t* vG     = (ushort_t*)(ws + OFF_V);
  ushort_t* Opart  = (ushort_t*)(ws + OFF_OP);
  float*    lpart  = (float*)(ws + OFF_LP);
  float*    e_buf  = (float*)(ws + OFF_EB);
  float*    sumExp = (float*)(ws + OFF_SE);

  wconv_kernel<<<144, 256, 0, stream>>>(Wq, Wk, Wv, W6, Wb);
  qkv_mfma<<<dim3(NT, 5), 256, 0, stream>>>(x, Wb, bq, bk, bv, qT, kT, vG, sumExp);
  attn_kernel<<<dim3(NT, nsl), 256, 0, stream>>>(qT, kT, vG, Opart, lpart, base, rem);
  if (nsl == 7) cco_kernel<7><<<NT, 1024, 0, stream>>>(Opart, lpart, e_buf, sumExp);
  else          cco_kernel<4><<<NT, 1024, 0, stream>>>(Opart, lpart, e_buf, sumExp);
  final_mfma<<<dim3(NT, 4), 256, 0, stream>>>(x, Wb + 81920, b6, gamma, e_buf, sumExp, out);
}